// Round 1
// baseline (1950.608 us; speedup 1.0000x reference)
//
#include <hip/hip_runtime.h>

static inline int ceil_div(int a, int b){ return (a+b-1)/b; }

// W[r][i][o] = sum_b comp[r][b] * basis[b][i][o]
__global__ void compute_W_kernel(const float* __restrict__ comp, const float* __restrict__ basis,
                                 float* __restrict__ W, int R, int B, int IO) {
    int idx = blockIdx.x*blockDim.x + threadIdx.x;
    if (idx >= R*IO) return;
    int r = idx / IO, io = idx - r*IO;
    float acc = 0.f;
    for (int b = 0; b < B; ++b) acc += comp[r*B+b] * basis[(size_t)b*IO + io];
    W[idx] = acc;
}

// cnt[d][r] += 1 per edge
__global__ void count_kernel(const int* __restrict__ dst, const int* __restrict__ etype,
                             float* __restrict__ cnt, int E, int R) {
    int e = blockIdx.x*blockDim.x + threadIdx.x;
    if (e >= E) return;
    atomicAdd(&cnt[(size_t)dst[e]*R + etype[e]], 1.0f);
}

// For relation r: S[dst] += x[src] / cnt[dst][r]   (D = 128 hardcoded: 32 lanes * float4)
__global__ void scatter_kernel(const float* __restrict__ x, const int* __restrict__ src,
                               const int* __restrict__ dst, const int* __restrict__ etype,
                               const float* __restrict__ cnt, float* __restrict__ S,
                               int E, int R, int r) {
    int t = blockIdx.x*blockDim.x + threadIdx.x;
    int e = t >> 5;
    if (e >= E) return;
    if (etype[e] != r) return;
    int lane = t & 31;
    int d = dst[e], s = src[e];
    float inv = 1.0f / cnt[(size_t)d*R + r];
    float4 v = reinterpret_cast<const float4*>(x)[(size_t)s*32 + lane];
    float* o = S + (size_t)d*128 + lane*4;
    atomicAdd(o+0, v.x*inv);
    atomicAdd(o+1, v.y*inv);
    atomicAdd(o+2, v.z*inv);
    atomicAdd(o+3, v.w*inv);
}

// out[M x 128]:
//   mode 0: out += A @ Bm
//   mode 1: out  = relu(A @ Bm + Cadd + bias)
// A: [M,128] row-major, Bm: [128,128] row-major.
__global__ __launch_bounds__(256)
void gemm128_kernel(const float* __restrict__ A, const float* __restrict__ Bm,
                    const float* __restrict__ Cadd, const float* __restrict__ bias,
                    float* __restrict__ out, int M, int mode) {
    __shared__ float AsT[32][132];   // [k][row], padded
    __shared__ float Bs[32][128];    // [k][col]
    int tid = threadIdx.x;
    int tx = tid & 15, ty = tid >> 4;     // 16 x 16 threads
    int bm = blockIdx.x * 128;
    float acc[8][8];
    #pragma unroll
    for (int i = 0; i < 8; ++i)
        #pragma unroll
        for (int j = 0; j < 8; ++j) acc[i][j] = 0.f;

    for (int kc = 0; kc < 128; kc += 32) {
        // Load A chunk (128 rows x 32 k) transposed into AsT[k][row]
        {
            int c4 = tid & 7;       // which float4 along k (8 * 4 = 32)
            int r0 = tid >> 3;      // 0..31
            #pragma unroll
            for (int p = 0; p < 4; ++p) {
                int row = r0 + p*32;
                int grow = bm + row;
                float4 v = make_float4(0.f,0.f,0.f,0.f);
                if (grow < M)
                    v = reinterpret_cast<const float4*>(A + (size_t)grow*128 + kc)[c4];
                AsT[c4*4+0][row] = v.x;
                AsT[c4*4+1][row] = v.y;
                AsT[c4*4+2][row] = v.z;
                AsT[c4*4+3][row] = v.w;
            }
        }
        // Load B chunk (32 k x 128 cols) linear
        {
            #pragma unroll
            for (int p = 0; p < 4; ++p) {
                int i4 = tid + p*256;       // float4 index into 32x128 chunk
                int kr = i4 >> 5;           // row within chunk (32 float4 per row)
                int c4 = i4 & 31;
                float4 v = reinterpret_cast<const float4*>(Bm + (size_t)(kc+kr)*128)[c4];
                reinterpret_cast<float4*>(&Bs[kr][0])[c4] = v;
            }
        }
        __syncthreads();
        #pragma unroll
        for (int k = 0; k < 32; ++k) {
            float a[8], b[8];
            float4 a0 = *reinterpret_cast<const float4*>(&AsT[k][ty*8]);
            float4 a1 = *reinterpret_cast<const float4*>(&AsT[k][ty*8+4]);
            float4 b0 = *reinterpret_cast<const float4*>(&Bs[k][tx*8]);
            float4 b1 = *reinterpret_cast<const float4*>(&Bs[k][tx*8+4]);
            a[0]=a0.x; a[1]=a0.y; a[2]=a0.z; a[3]=a0.w;
            a[4]=a1.x; a[5]=a1.y; a[6]=a1.z; a[7]=a1.w;
            b[0]=b0.x; b[1]=b0.y; b[2]=b0.z; b[3]=b0.w;
            b[4]=b1.x; b[5]=b1.y; b[6]=b1.z; b[7]=b1.w;
            #pragma unroll
            for (int i = 0; i < 8; ++i)
                #pragma unroll
                for (int j = 0; j < 8; ++j)
                    acc[i][j] += a[i]*b[j];
        }
        __syncthreads();
    }
    // Epilogue
    #pragma unroll
    for (int i = 0; i < 8; ++i) {
        int grow = bm + ty*8 + i;
        if (grow >= M) continue;
        float* po = out + (size_t)grow*128 + tx*8;
        if (mode == 0) {
            float4 o0 = *reinterpret_cast<float4*>(po);
            float4 o1 = *reinterpret_cast<float4*>(po+4);
            o0.x += acc[i][0]; o0.y += acc[i][1]; o0.z += acc[i][2]; o0.w += acc[i][3];
            o1.x += acc[i][4]; o1.y += acc[i][5]; o1.z += acc[i][6]; o1.w += acc[i][7];
            *reinterpret_cast<float4*>(po)   = o0;
            *reinterpret_cast<float4*>(po+4) = o1;
        } else {
            const float* pc = Cadd + (size_t)grow*128 + tx*8;
            float4 c0 = *reinterpret_cast<const float4*>(pc);
            float4 c1 = *reinterpret_cast<const float4*>(pc+4);
            float4 bb0 = *reinterpret_cast<const float4*>(bias + tx*8);
            float4 bb1 = *reinterpret_cast<const float4*>(bias + tx*8 + 4);
            float4 o0, o1;
            o0.x = fmaxf(acc[i][0]+c0.x+bb0.x, 0.f);
            o0.y = fmaxf(acc[i][1]+c0.y+bb0.y, 0.f);
            o0.z = fmaxf(acc[i][2]+c0.z+bb0.z, 0.f);
            o0.w = fmaxf(acc[i][3]+c0.w+bb0.w, 0.f);
            o1.x = fmaxf(acc[i][4]+c1.x+bb1.x, 0.f);
            o1.y = fmaxf(acc[i][5]+c1.y+bb1.y, 0.f);
            o1.z = fmaxf(acc[i][6]+c1.z+bb1.z, 0.f);
            o1.w = fmaxf(acc[i][7]+c1.w+bb1.w, 0.f);
            *reinterpret_cast<float4*>(po)   = o0;
            *reinterpret_cast<float4*>(po+4) = o1;
        }
    }
}

// psum[batch[n]] += h[n]; gcnt[batch[n]] += 1
__global__ void pool_kernel(const float* __restrict__ h, const int* __restrict__ batch,
                            float* __restrict__ psum, float* __restrict__ gcnt, int N) {
    int t = blockIdx.x*blockDim.x + threadIdx.x;
    int n = t >> 5;
    if (n >= N) return;
    int lane = t & 31;
    int g = batch[n];
    float4 v = reinterpret_cast<const float4*>(h)[(size_t)n*32 + lane];
    float* o = psum + (size_t)g*128 + lane*4;
    atomicAdd(o+0, v.x);
    atomicAdd(o+1, v.y);
    atomicAdd(o+2, v.z);
    atomicAdd(o+3, v.w);
    if (lane == 0) atomicAdd(&gcnt[g], 1.0f);
}

// out[g][c] = sum_k psum[g][k]/max(gcnt[g],1) * fc_w[k][c] + fc_b[c]
__global__ void fc_kernel(const float* __restrict__ psum, const float* __restrict__ gcnt,
                          const float* __restrict__ fw, const float* __restrict__ fb,
                          float* __restrict__ out, int G, int D, int C) {
    int idx = blockIdx.x*blockDim.x + threadIdx.x;
    if (idx >= G*C) return;
    int g = idx / C, c = idx - g*C;
    float inv = 1.0f / fmaxf(gcnt[g], 1.0f);
    float acc = fb[c];
    for (int k = 0; k < D; ++k)
        acc += psum[(size_t)g*D + k] * inv * fw[(size_t)k*C + c];
    out[idx] = acc;
}

extern "C" void kernel_launch(void* const* d_in, const int* in_sizes, int n_in,
                              void* d_out, int out_size, void* d_ws, size_t ws_size,
                              hipStream_t stream) {
    const float* x       = (const float*)d_in[0];
    const int*   eindex  = (const int*)  d_in[1];
    const int*   etype   = (const int*)  d_in[2];
    // d_in[3] edge_attr: unused by reference
    const int*   batch   = (const int*)  d_in[4];
    // d_in[5] num_graphs: derived from out_size instead
    const float* basis   = (const float*)d_in[6];
    const float* comp    = (const float*)d_in[7];
    const float* root    = (const float*)d_in[8];
    const float* bias    = (const float*)d_in[9];
    const float* fc_w    = (const float*)d_in[10];
    const float* fc_b    = (const float*)d_in[11];

    int N  = in_sizes[4];
    int E  = in_sizes[2];
    int D  = in_sizes[0] / N;      // 128
    int C  = in_sizes[11];         // 16
    int G  = out_size / C;         // 64
    int IO = in_sizes[8];          // D_IN * D_H = 16384
    int B  = in_sizes[6] / IO;     // 4
    int R  = in_sizes[7] / B;      // 8

    const int* src = eindex;
    const int* dst = eindex + E;

    float* ws   = (float*)d_ws;
    float* W    = ws;                       // R*IO
    float* cnt  = W    + (size_t)R*IO;      // N*R
    float* S    = cnt  + (size_t)N*R;       // N*D  (reused later as h)
    float* agg  = S    + (size_t)N*D;       // N*D
    float* psum = agg  + (size_t)N*D;       // G*D
    float* gcnt = psum + (size_t)G*D;       // G

    hipMemsetAsync(cnt,  0, sizeof(float)*(size_t)N*R, stream);
    hipMemsetAsync(agg,  0, sizeof(float)*(size_t)N*D, stream);
    hipMemsetAsync(psum, 0, sizeof(float)*((size_t)G*D + G), stream);

    compute_W_kernel<<<ceil_div(R*IO,256),256,0,stream>>>(comp, basis, W, R, B, IO);
    count_kernel<<<ceil_div(E,256),256,0,stream>>>(dst, etype, cnt, E, R);

    for (int r = 0; r < R; ++r) {
        hipMemsetAsync(S, 0, sizeof(float)*(size_t)N*D, stream);
        scatter_kernel<<<ceil_div(E*32,256),256,0,stream>>>(x, src, dst, etype, cnt, S, E, R, r);
        gemm128_kernel<<<ceil_div(N,128),256,0,stream>>>(S, W + (size_t)r*IO, nullptr, nullptr, agg, N, 0);
    }
    // h = relu(x @ root + agg + bias), written into S (free now)
    gemm128_kernel<<<ceil_div(N,128),256,0,stream>>>(x, root, agg, bias, S, N, 1);

    pool_kernel<<<ceil_div(N*32,256),256,0,stream>>>(S, batch, psum, gcnt, N);
    fc_kernel<<<ceil_div(G*C,256),256,0,stream>>>(psum, gcnt, fc_w, fc_b, (float*)d_out, G, D, C);
}

// Round 2
// 459.838 us; speedup vs baseline: 4.2420x; 4.2420x over previous
//
#include <hip/hip_runtime.h>

static inline int ceil_div(int a, int b){ return (a+b-1)/b; }
static inline size_t align_up(size_t x, size_t a){ return (x + a - 1) / a * a; }

static __device__ inline unsigned short f2bf(float f){
    unsigned int u = __float_as_uint(f);
    unsigned int lsb = (u >> 16) & 1u;
    u += 0x7FFFu + lsb;
    return (unsigned short)(u >> 16);
}
static __device__ inline float bf2f(unsigned short b){
    return __uint_as_float(((unsigned int)b) << 16);
}

// W[r][i][o] = sum_b comp[r][b] * basis[b][i][o]  -> contiguous [R*128,128] = Wstack
__global__ void compute_W_kernel(const float* __restrict__ comp, const float* __restrict__ basis,
                                 float* __restrict__ W, int R, int B, int IO) {
    int idx = blockIdx.x*blockDim.x + threadIdx.x;
    if (idx >= R*IO) return;
    int r = idx / IO;
    float acc = 0.f;
    for (int b = 0; b < B; ++b) acc += comp[r*B+b] * basis[(size_t)b*IO + (idx - r*IO)];
    W[idx] = acc;
}

// integer histogram over (dst, rel) bins
__global__ void count_kernel(const int* __restrict__ dst, const int* __restrict__ et,
                             int* __restrict__ cnt, int E, int R) {
    int e = blockIdx.x*blockDim.x + threadIdx.x;
    if (e >= E) return;
    atomicAdd(&cnt[(size_t)dst[e]*R + et[e]], 1);
}

// exclusive scan, 1024 elements per block, 256 threads. bsums (optional) gets block totals.
__global__ __launch_bounds__(256)
void scan_block_kernel(const int* __restrict__ in, int* __restrict__ out,
                       int* __restrict__ bsums, int n) {
    __shared__ int tsum[256];
    int t = threadIdx.x;
    int idx0 = blockIdx.x*1024 + t*4;
    int v0 = (idx0+0 < n) ? in[idx0+0] : 0;
    int v1 = (idx0+1 < n) ? in[idx0+1] : 0;
    int v2 = (idx0+2 < n) ? in[idx0+2] : 0;
    int v3 = (idx0+3 < n) ? in[idx0+3] : 0;
    int s = v0+v1+v2+v3;
    tsum[t] = s; __syncthreads();
    for (int off = 1; off < 256; off <<= 1) {
        int x = (t >= off) ? tsum[t-off] : 0;
        __syncthreads();
        tsum[t] += x;
        __syncthreads();
    }
    int run = tsum[t] - s;   // exclusive prefix of this thread within block
    if (idx0+0 < n) out[idx0+0] = run; run += v0;
    if (idx0+1 < n) out[idx0+1] = run; run += v1;
    if (idx0+2 < n) out[idx0+2] = run; run += v2;
    if (idx0+3 < n) out[idx0+3] = run;
    if (bsums && t == 255) bsums[blockIdx.x] = tsum[255];
}

// out[i] += bs[i/1024]; also out[n] = total
__global__ void scan_add_kernel(int* __restrict__ out, const int* __restrict__ bs,
                                int n, int total) {
    int i = blockIdx.x*blockDim.x + threadIdx.x;
    if (i < n) out[i] += bs[i >> 10];
    if (i == 0) out[n] = total;
}

// slot_src[offsets[bin] + cursor[bin]++] = src[e]
__global__ void fill_kernel(const int* __restrict__ src, const int* __restrict__ dst,
                            const int* __restrict__ et, const int* __restrict__ offsets,
                            int* __restrict__ cursor, int* __restrict__ slot_src,
                            int E, int R) {
    int e = blockIdx.x*blockDim.x + threadIdx.x;
    if (e >= E) return;
    int bin = dst[e]*R + et[e];
    int slot = offsets[bin] + atomicAdd(&cursor[bin], 1);
    slot_src[slot] = src[e];
}

// One wave (64 lanes) per node: per relation mean of x[src] -> Mc bf16 [N, RC*128]
__global__ __launch_bounds__(256)
void aggregate_kernel(const float* __restrict__ x, const int* __restrict__ offsets,
                      const int* __restrict__ slot_src, unsigned int* __restrict__ Mc,
                      int N, int R, int rlo, int RC) {
    int widx = (int)((blockIdx.x*blockDim.x + threadIdx.x) >> 6);
    if (widx >= N) return;
    int lane = threadIdx.x & 63;
    int KA = RC*128;
    unsigned int* Mrow = Mc + (((size_t)widx*KA) >> 1);
    for (int rr = 0; rr < RC; ++rr) {
        int bin = widx*R + rlo + rr;
        int s0 = offsets[bin], s1 = offsets[bin+1];
        float inv = 1.0f / fmaxf((float)(s1 - s0), 1.0f);
        float ax = 0.f, ay = 0.f;
        for (int e = s0; e < s1; ++e) {
            int s = slot_src[e];
            float2 v = reinterpret_cast<const float2*>(x + (size_t)s*128)[lane];
            ax += v.x; ay += v.y;
        }
        ax *= inv; ay *= inv;
        Mrow[rr*64 + lane] = (unsigned int)f2bf(ax) | ((unsigned int)f2bf(ay) << 16);
    }
}

// agg[M,128] += A(bf16)[M,KA] @ B(f32)[KA,128]
__global__ __launch_bounds__(256)
void gemm_agg_kernel(const unsigned short* __restrict__ A, const float* __restrict__ Bm,
                     float* __restrict__ out, int M, int KA) {
    __shared__ float AsT[32][132];
    __shared__ float Bs[32][128];
    int tid = threadIdx.x;
    int tx = tid & 15, ty = tid >> 4;
    int bm = blockIdx.x * 128;
    float acc[8][8];
    #pragma unroll
    for (int i = 0; i < 8; ++i)
        #pragma unroll
        for (int j = 0; j < 8; ++j) acc[i][j] = 0.f;

    for (int kc = 0; kc < KA; kc += 32) {
        int c4 = tid & 7;
        int r0 = tid >> 3;
        #pragma unroll
        for (int p = 0; p < 4; ++p) {
            int row = r0 + p*32;
            int grow = bm + row;
            ushort4 v = make_ushort4(0,0,0,0);
            if (grow < M)
                v = reinterpret_cast<const ushort4*>(A + (size_t)grow*KA + kc)[c4];
            AsT[c4*4+0][row] = bf2f(v.x);
            AsT[c4*4+1][row] = bf2f(v.y);
            AsT[c4*4+2][row] = bf2f(v.z);
            AsT[c4*4+3][row] = bf2f(v.w);
        }
        #pragma unroll
        for (int p = 0; p < 4; ++p) {
            int i4 = tid + p*256;
            int kr = i4 >> 5;
            int cc = i4 & 31;
            float4 v = reinterpret_cast<const float4*>(Bm + (size_t)(kc+kr)*128)[cc];
            reinterpret_cast<float4*>(&Bs[kr][0])[cc] = v;
        }
        __syncthreads();
        #pragma unroll
        for (int k = 0; k < 32; ++k) {
            float a[8], b[8];
            float4 a0 = *reinterpret_cast<const float4*>(&AsT[k][ty*8]);
            float4 a1 = *reinterpret_cast<const float4*>(&AsT[k][ty*8+4]);
            float4 b0 = *reinterpret_cast<const float4*>(&Bs[k][tx*8]);
            float4 b1 = *reinterpret_cast<const float4*>(&Bs[k][tx*8+4]);
            a[0]=a0.x; a[1]=a0.y; a[2]=a0.z; a[3]=a0.w;
            a[4]=a1.x; a[5]=a1.y; a[6]=a1.z; a[7]=a1.w;
            b[0]=b0.x; b[1]=b0.y; b[2]=b0.z; b[3]=b0.w;
            b[4]=b1.x; b[5]=b1.y; b[6]=b1.z; b[7]=b1.w;
            #pragma unroll
            for (int i = 0; i < 8; ++i)
                #pragma unroll
                for (int j = 0; j < 8; ++j)
                    acc[i][j] += a[i]*b[j];
        }
        __syncthreads();
    }
    #pragma unroll
    for (int i = 0; i < 8; ++i) {
        int grow = bm + ty*8 + i;
        if (grow >= M) continue;
        float* po = out + (size_t)grow*128 + tx*8;
        float4 o0 = *reinterpret_cast<float4*>(po);
        float4 o1 = *reinterpret_cast<float4*>(po+4);
        o0.x += acc[i][0]; o0.y += acc[i][1]; o0.z += acc[i][2]; o0.w += acc[i][3];
        o1.x += acc[i][4]; o1.y += acc[i][5]; o1.z += acc[i][6]; o1.w += acc[i][7];
        *reinterpret_cast<float4*>(po)   = o0;
        *reinterpret_cast<float4*>(po+4) = o1;
    }
}

// h = relu(x @ root + Cadd + bias), safe for out == Cadd (in-place)
__global__ __launch_bounds__(256)
void gemm_h_kernel(const float* __restrict__ A, const float* __restrict__ Bm,
                   const float* __restrict__ Cadd, const float* __restrict__ bias,
                   float* __restrict__ out, int M) {
    __shared__ float AsT[32][132];
    __shared__ float Bs[32][128];
    int tid = threadIdx.x;
    int tx = tid & 15, ty = tid >> 4;
    int bm = blockIdx.x * 128;
    float acc[8][8];
    #pragma unroll
    for (int i = 0; i < 8; ++i)
        #pragma unroll
        for (int j = 0; j < 8; ++j) acc[i][j] = 0.f;

    for (int kc = 0; kc < 128; kc += 32) {
        int c4 = tid & 7;
        int r0 = tid >> 3;
        #pragma unroll
        for (int p = 0; p < 4; ++p) {
            int row = r0 + p*32;
            int grow = bm + row;
            float4 v = make_float4(0.f,0.f,0.f,0.f);
            if (grow < M)
                v = reinterpret_cast<const float4*>(A + (size_t)grow*128 + kc)[c4];
            AsT[c4*4+0][row] = v.x;
            AsT[c4*4+1][row] = v.y;
            AsT[c4*4+2][row] = v.z;
            AsT[c4*4+3][row] = v.w;
        }
        #pragma unroll
        for (int p = 0; p < 4; ++p) {
            int i4 = tid + p*256;
            int kr = i4 >> 5;
            int cc = i4 & 31;
            float4 v = reinterpret_cast<const float4*>(Bm + (size_t)(kc+kr)*128)[cc];
            reinterpret_cast<float4*>(&Bs[kr][0])[cc] = v;
        }
        __syncthreads();
        #pragma unroll
        for (int k = 0; k < 32; ++k) {
            float a[8], b[8];
            float4 a0 = *reinterpret_cast<const float4*>(&AsT[k][ty*8]);
            float4 a1 = *reinterpret_cast<const float4*>(&AsT[k][ty*8+4]);
            float4 b0 = *reinterpret_cast<const float4*>(&Bs[k][tx*8]);
            float4 b1 = *reinterpret_cast<const float4*>(&Bs[k][tx*8+4]);
            a[0]=a0.x; a[1]=a0.y; a[2]=a0.z; a[3]=a0.w;
            a[4]=a1.x; a[5]=a1.y; a[6]=a1.z; a[7]=a1.w;
            b[0]=b0.x; b[1]=b0.y; b[2]=b0.z; b[3]=b0.w;
            b[4]=b1.x; b[5]=b1.y; b[6]=b1.z; b[7]=b1.w;
            #pragma unroll
            for (int i = 0; i < 8; ++i)
                #pragma unroll
                for (int j = 0; j < 8; ++j)
                    acc[i][j] += a[i]*b[j];
        }
        __syncthreads();
    }
    #pragma unroll
    for (int i = 0; i < 8; ++i) {
        int grow = bm + ty*8 + i;
        if (grow >= M) continue;
        float* po = out + (size_t)grow*128 + tx*8;
        const float* pc = Cadd + (size_t)grow*128 + tx*8;
        float4 c0 = *reinterpret_cast<const float4*>(pc);
        float4 c1 = *reinterpret_cast<const float4*>(pc+4);
        float4 bb0 = *reinterpret_cast<const float4*>(bias + tx*8);
        float4 bb1 = *reinterpret_cast<const float4*>(bias + tx*8 + 4);
        float4 o0, o1;
        o0.x = fmaxf(acc[i][0]+c0.x+bb0.x, 0.f);
        o0.y = fmaxf(acc[i][1]+c0.y+bb0.y, 0.f);
        o0.z = fmaxf(acc[i][2]+c0.z+bb0.z, 0.f);
        o0.w = fmaxf(acc[i][3]+c0.w+bb0.w, 0.f);
        o1.x = fmaxf(acc[i][4]+c1.x+bb1.x, 0.f);
        o1.y = fmaxf(acc[i][5]+c1.y+bb1.y, 0.f);
        o1.z = fmaxf(acc[i][6]+c1.z+bb1.z, 0.f);
        o1.w = fmaxf(acc[i][7]+c1.w+bb1.w, 0.f);
        *reinterpret_cast<float4*>(po)   = o0;
        *reinterpret_cast<float4*>(po+4) = o1;
    }
}

// start[g] = first index with batch[idx] >= g (batch sorted); start[G] = N
__global__ void bounds_kernel(const int* __restrict__ batch, int* __restrict__ start,
                              int N, int G) {
    int g = blockIdx.x*blockDim.x + threadIdx.x;
    if (g > G) return;
    if (g == G) { start[G] = N; return; }
    int lo = 0, hi = N;
    while (lo < hi) { int mid = (lo+hi) >> 1; if (batch[mid] < g) lo = mid+1; else hi = mid; }
    start[g] = lo;
}

// psum[g] = sum of h rows in [start[g], start[g+1]) ; grid (G, NCHUNK)
__global__ __launch_bounds__(256)
void pool_kernel2(const float* __restrict__ h, const int* __restrict__ start,
                  float* __restrict__ psum) {
    int g = blockIdx.x;
    int chunk = blockIdx.y, NC = gridDim.y;
    int s0 = start[g], s1 = start[g+1], len = s1 - s0;
    int a = s0 + (int)((long long)len * chunk / NC);
    int b = s0 + (int)((long long)len * (chunk+1) / NC);
    int t = threadIdx.x;
    int d = t & 127;
    float acc = 0.f;
    for (int row = a + (t >> 7); row < b; row += 2)
        acc += h[(size_t)row*128 + d];
    atomicAdd(&psum[(size_t)g*128 + d], acc);
}

__global__ void fc_kernel(const float* __restrict__ psum, const int* __restrict__ start,
                          const float* __restrict__ fw, const float* __restrict__ fb,
                          float* __restrict__ out, int G, int D, int C) {
    int idx = blockIdx.x*blockDim.x + threadIdx.x;
    if (idx >= G*C) return;
    int g = idx / C, c = idx - g*C;
    float inv = 1.0f / fmaxf((float)(start[g+1] - start[g]), 1.0f);
    float acc = fb[c];
    for (int k = 0; k < D; ++k)
        acc += psum[(size_t)g*D + k] * inv * fw[(size_t)k*C + c];
    out[idx] = acc;
}

extern "C" void kernel_launch(void* const* d_in, const int* in_sizes, int n_in,
                              void* d_out, int out_size, void* d_ws, size_t ws_size,
                              hipStream_t stream) {
    const float* x       = (const float*)d_in[0];
    const int*   eindex  = (const int*)  d_in[1];
    const int*   etype   = (const int*)  d_in[2];
    const int*   batch   = (const int*)  d_in[4];
    const float* basis   = (const float*)d_in[6];
    const float* comp    = (const float*)d_in[7];
    const float* root    = (const float*)d_in[8];
    const float* bias    = (const float*)d_in[9];
    const float* fc_w    = (const float*)d_in[10];
    const float* fc_b    = (const float*)d_in[11];

    int N  = in_sizes[4];
    int E  = in_sizes[2];
    int C  = in_sizes[11];
    int G  = out_size / C;
    int IO = in_sizes[8];          // 128*128
    int B  = in_sizes[6] / IO;     // 4
    int R  = in_sizes[7] / B;      // 8
    int NR = N * R;

    const int* src = eindex;
    const int* dst = eindex + E;

    // ---- workspace layout ----
    char* base = (char*)d_ws;
    size_t off = 0;
    auto alloc = [&](size_t bytes) -> char* {
        char* p = base + off;
        off = align_up(off + bytes, 256);
        return p;
    };
    float* W        = (float*)alloc(sizeof(float)*(size_t)R*IO);
    int*   cnt      = (int*)  alloc(sizeof(int)*(size_t)NR);       // also cursor
    int*   offsets  = (int*)  alloc(sizeof(int)*((size_t)NR+1));
    int*   bsums    = (int*)  alloc(sizeof(int)*1024);
    int*   slot_src = (int*)  alloc(sizeof(int)*(size_t)E);
    float* agg      = (float*)alloc(sizeof(float)*(size_t)N*128);  // becomes h in-place
    float* psum     = (float*)alloc(sizeof(float)*(size_t)G*128);
    int*   start    = (int*)  alloc(sizeof(int)*((size_t)G+1));
    size_t remain = (ws_size > off) ? (ws_size - off) : 0;
    int RC = 8;
    while (RC > 1 && sizeof(unsigned short)*(size_t)N*RC*128 > remain) RC >>= 1;
    unsigned int* Mc = (unsigned int*)alloc(sizeof(unsigned short)*(size_t)N*RC*128);

    // ---- pipeline ----
    hipMemsetAsync(cnt, 0, sizeof(int)*(size_t)NR, stream);
    compute_W_kernel<<<ceil_div(R*IO,256),256,0,stream>>>(comp, basis, W, R, B, IO);
    count_kernel<<<ceil_div(E,256),256,0,stream>>>(dst, etype, cnt, E, R);

    int nb = ceil_div(NR, 1024);
    scan_block_kernel<<<nb,256,0,stream>>>(cnt, offsets, bsums, NR);
    scan_block_kernel<<<1,256,0,stream>>>(bsums, bsums, nullptr, nb);
    scan_add_kernel<<<ceil_div(NR,256),256,0,stream>>>(offsets, bsums, NR, E);

    hipMemsetAsync(cnt, 0, sizeof(int)*(size_t)NR, stream);  // reuse as cursor
    fill_kernel<<<ceil_div(E,256),256,0,stream>>>(src, dst, etype, offsets, cnt, slot_src, E, R);

    hipMemsetAsync(agg, 0, sizeof(float)*(size_t)N*128, stream);
    int KA = RC*128;
    for (int rlo = 0; rlo < R; rlo += RC) {
        aggregate_kernel<<<ceil_div(N*64,256),256,0,stream>>>(x, offsets, slot_src, Mc, N, R, rlo, RC);
        gemm_agg_kernel<<<ceil_div(N,128),256,0,stream>>>((const unsigned short*)Mc,
                                                          W + (size_t)rlo*IO, agg, N, KA);
    }
    // h = relu(x@root + agg + bias), in place into agg
    gemm_h_kernel<<<ceil_div(N,128),256,0,stream>>>(x, root, agg, bias, agg, N);

    hipMemsetAsync(psum, 0, sizeof(float)*(size_t)G*128, stream);
    bounds_kernel<<<1,128,0,stream>>>(batch, start, N, G);
    pool_kernel2<<<dim3(G,8),256,0,stream>>>(agg, start, psum);
    fc_kernel<<<ceil_div(G*C,256),256,0,stream>>>(psum, start, fc_w, fc_b, (float*)d_out, G, C > 0 ? 128 : 128, C);
}

// Round 3
// 293.220 us; speedup vs baseline: 6.6524x; 1.5682x over previous
//
#include <hip/hip_runtime.h>

static inline int ceil_div(int a, int b){ return (a+b-1)/b; }
static inline size_t align_up(size_t x, size_t a){ return (x + a - 1) / a * a; }

typedef __bf16 bf16x8 __attribute__((ext_vector_type(8)));
typedef float  f32x4  __attribute__((ext_vector_type(4)));

static __device__ inline unsigned short f2bf(float f){
    unsigned int u = __float_as_uint(f);
    unsigned int lsb = (u >> 16) & 1u;
    u += 0x7FFFu + lsb;
    return (unsigned short)(u >> 16);
}
static __device__ inline float bf2f(unsigned short b){
    return __uint_as_float(((unsigned int)b) << 16);
}
static __device__ inline unsigned int packbf(float a, float b){
    return (unsigned int)f2bf(a) | ((unsigned int)f2bf(b) << 16);
}

// Bt[o][kk] bf16, o in [0,128), kk in [0,1152):
//   kk < 1024: W[r=kk>>7][i=kk&127][o] = sum_b comp[r][b]*basis[b][i][o]
//   kk >= 1024: root[kk-1024][o]
__global__ void compute_Bt_kernel(const float* __restrict__ comp, const float* __restrict__ basis,
                                  const float* __restrict__ root, unsigned short* __restrict__ Bt,
                                  int B) {
    int idx = blockIdx.x*blockDim.x + threadIdx.x;
    if (idx >= 128*1152) return;
    int o = idx / 1152, kk = idx - o*1152;
    float val;
    if (kk < 1024) {
        int r = kk >> 7, i = kk & 127;
        val = 0.f;
        for (int b = 0; b < B; ++b)
            val += comp[r*B+b] * basis[((size_t)b*128 + i)*128 + o];
    } else {
        val = root[(size_t)(kk-1024)*128 + o];
    }
    Bt[idx] = f2bf(val);
}

// integer histogram over (dst, rel) bins
__global__ void count_kernel(const int* __restrict__ dst, const int* __restrict__ et,
                             int* __restrict__ cnt, int E, int R) {
    int e = blockIdx.x*blockDim.x + threadIdx.x;
    if (e >= E) return;
    atomicAdd(&cnt[(size_t)dst[e]*R + et[e]], 1);
}

// exclusive scan, 1024 elements per block, 256 threads.
__global__ __launch_bounds__(256)
void scan_block_kernel(const int* __restrict__ in, int* __restrict__ out,
                       int* __restrict__ bsums, int n) {
    __shared__ int tsum[256];
    int t = threadIdx.x;
    int idx0 = blockIdx.x*1024 + t*4;
    int v0 = (idx0+0 < n) ? in[idx0+0] : 0;
    int v1 = (idx0+1 < n) ? in[idx0+1] : 0;
    int v2 = (idx0+2 < n) ? in[idx0+2] : 0;
    int v3 = (idx0+3 < n) ? in[idx0+3] : 0;
    int s = v0+v1+v2+v3;
    tsum[t] = s; __syncthreads();
    for (int off = 1; off < 256; off <<= 1) {
        int x = (t >= off) ? tsum[t-off] : 0;
        __syncthreads();
        tsum[t] += x;
        __syncthreads();
    }
    int run = tsum[t] - s;
    if (idx0+0 < n) out[idx0+0] = run; run += v0;
    if (idx0+1 < n) out[idx0+1] = run; run += v1;
    if (idx0+2 < n) out[idx0+2] = run; run += v2;
    if (idx0+3 < n) out[idx0+3] = run;
    if (bsums && t == 255) bsums[blockIdx.x] = tsum[255];
}

__global__ void scan_add_kernel(int* __restrict__ out, const int* __restrict__ bs,
                                int n, int total) {
    int i = blockIdx.x*blockDim.x + threadIdx.x;
    if (i < n) out[i] += bs[i >> 10];
    if (i == 0) out[n] = total;
}

__global__ void fill_kernel(const int* __restrict__ src, const int* __restrict__ dst,
                            const int* __restrict__ et, const int* __restrict__ offsets,
                            int* __restrict__ cursor, int* __restrict__ slot_src,
                            int E, int R) {
    int e = blockIdx.x*blockDim.x + threadIdx.x;
    if (e >= E) return;
    int bin = dst[e]*R + et[e];
    int slot = offsets[bin] + atomicAdd(&cursor[bin], 1);
    slot_src[slot] = src[e];
}

// x (f32) -> bf16 pairs into Mc columns 1024..1151 (u32 slots 512..575 of each 576-u32 row)
__global__ __launch_bounds__(256)
void xb_kernel(const float* __restrict__ x, unsigned int* __restrict__ Mc, int N) {
    int t = blockIdx.x*blockDim.x + threadIdx.x;
    int n = t >> 6;
    if (n >= N) return;
    int l = t & 63;
    float2 v = reinterpret_cast<const float2*>(x + (size_t)n*128)[l];
    Mc[(size_t)n*576 + 512 + l] = packbf(v.x, v.y);
}

// One wave per node: per-relation means (gather bf16 rows from Mc's x-region)
// into Mc u32 slots 0..511.
__global__ __launch_bounds__(256)
void aggregate_kernel(const int* __restrict__ offsets, const int* __restrict__ slot_src,
                      unsigned int* __restrict__ Mc, int N, int R) {
    int w = (int)((blockIdx.x*blockDim.x + threadIdx.x) >> 6);
    if (w >= N) return;
    int l = threadIdx.x & 63;
    unsigned int* Mrow = Mc + (size_t)w*576;
    for (int rr = 0; rr < R; ++rr) {
        int bin = w*R + rr;
        int s0 = offsets[bin], s1 = offsets[bin+1];
        float inv = 1.0f / fmaxf((float)(s1 - s0), 1.0f);
        float ax = 0.f, ay = 0.f;
        for (int e = s0; e < s1; ++e) {
            int s = slot_src[e];
            unsigned int u = Mc[(size_t)s*576 + 512 + l];
            ax += bf2f((unsigned short)(u & 0xFFFFu));
            ay += bf2f((unsigned short)(u >> 16));
        }
        Mrow[rr*64 + l] = packbf(ax*inv, ay*inv);
    }
}

// h(bf16)[M,128] = relu( A(bf16)[M,1152] @ Bt^T + bias ), Bt stored [128][1152]
// MFMA 16x16x32 bf16; block = 4 waves, wave = 32 rows x 128 cols; no LDS.
__global__ __launch_bounds__(256)
void mfma_gemm_kernel(const unsigned short* __restrict__ Ac,
                      const unsigned short* __restrict__ Btc,
                      const float* __restrict__ bias,
                      unsigned short* __restrict__ h, int M) {
    constexpr int KA = 1152;
    int lane = threadIdx.x & 63;
    int wid  = threadIdx.x >> 6;
    int fr   = lane & 15;          // M-row within frag / N-col within frag
    int kb   = lane >> 4;          // 0..3 (k-block)
    long m0 = (long)blockIdx.x*128 + wid*32;

    const bf16x8* ap0 = reinterpret_cast<const bf16x8*>(Ac + (size_t)(m0 + fr)*KA + kb*8);
    const bf16x8* ap1 = reinterpret_cast<const bf16x8*>(Ac + (size_t)(m0 + 16 + fr)*KA + kb*8);
    const bf16x8* bp  = reinterpret_cast<const bf16x8*>(Btc + (size_t)fr*KA + kb*8);

    f32x4 acc0[8], acc1[8];
    #pragma unroll
    for (int nf = 0; nf < 8; ++nf) {
        acc0[nf] = f32x4{0.f,0.f,0.f,0.f};
        acc1[nf] = f32x4{0.f,0.f,0.f,0.f};
    }

    #pragma unroll 2
    for (int ks = 0; ks < KA/32; ++ks) {
        bf16x8 a0 = ap0[ks*4];     // +4 bf16x8 = 32 elements
        bf16x8 a1 = ap1[ks*4];
        #pragma unroll
        for (int nf = 0; nf < 8; ++nf) {
            bf16x8 b = bp[(size_t)nf*16*(KA/8) + ks*4];
            acc0[nf] = __builtin_amdgcn_mfma_f32_16x16x32_bf16(a0, b, acc0[nf], 0, 0, 0);
            acc1[nf] = __builtin_amdgcn_mfma_f32_16x16x32_bf16(a1, b, acc1[nf], 0, 0, 0);
        }
    }

    float bb[8];
    #pragma unroll
    for (int nf = 0; nf < 8; ++nf) bb[nf] = bias[nf*16 + fr];

    #pragma unroll
    for (int mf = 0; mf < 2; ++mf) {
        #pragma unroll
        for (int q = 0; q < 4; ++q) {
            long r = m0 + mf*16 + kb*4 + q;
            if (r >= M) continue;
            unsigned short* hr = h + (size_t)r*128;
            #pragma unroll
            for (int nf = 0; nf < 8; ++nf) {
                float v = (mf ? acc1[nf][q] : acc0[nf][q]) + bb[nf];
                hr[nf*16 + fr] = f2bf(fmaxf(v, 0.f));
            }
        }
    }
}

// start[g] = first index with batch[idx] >= g (batch sorted); start[G] = N
__global__ void bounds_kernel(const int* __restrict__ batch, int* __restrict__ start,
                              int N, int G) {
    int g = blockIdx.x*blockDim.x + threadIdx.x;
    if (g > G) return;
    if (g == G) { start[G] = N; return; }
    int lo = 0, hi = N;
    while (lo < hi) { int mid = (lo+hi) >> 1; if (batch[mid] < g) lo = mid+1; else hi = mid; }
    start[g] = lo;
}

// psum[g][c] = sum of bf16 h rows in [start[g], start[g+1]); grid (G, NC)
__global__ __launch_bounds__(256)
void pool_kernel2(const unsigned int* __restrict__ h2, const int* __restrict__ start,
                  float* __restrict__ psum) {
    int g = blockIdx.x;
    int chunk = blockIdx.y, NC = gridDim.y;
    int s0 = start[g], s1 = start[g+1], len = s1 - s0;
    int a = s0 + (int)((long long)len * chunk / NC);
    int b = s0 + (int)((long long)len * (chunk+1) / NC);
    int t = threadIdx.x;
    int d2 = t & 63;
    float ax = 0.f, ay = 0.f;
    for (int row = a + (t >> 6); row < b; row += 4) {
        unsigned int u = h2[(size_t)row*64 + d2];
        ax += bf2f((unsigned short)(u & 0xFFFFu));
        ay += bf2f((unsigned short)(u >> 16));
    }
    atomicAdd(&psum[(size_t)g*128 + 2*d2    ], ax);
    atomicAdd(&psum[(size_t)g*128 + 2*d2 + 1], ay);
}

__global__ void fc_kernel(const float* __restrict__ psum, const int* __restrict__ start,
                          const float* __restrict__ fw, const float* __restrict__ fb,
                          float* __restrict__ out, int G, int D, int C) {
    int idx = blockIdx.x*blockDim.x + threadIdx.x;
    if (idx >= G*C) return;
    int g = idx / C, c = idx - g*C;
    float inv = 1.0f / fmaxf((float)(start[g+1] - start[g]), 1.0f);
    float acc = fb[c];
    for (int k = 0; k < D; ++k)
        acc += psum[(size_t)g*D + k] * inv * fw[(size_t)k*C + c];
    out[idx] = acc;
}

extern "C" void kernel_launch(void* const* d_in, const int* in_sizes, int n_in,
                              void* d_out, int out_size, void* d_ws, size_t ws_size,
                              hipStream_t stream) {
    const float* x       = (const float*)d_in[0];
    const int*   eindex  = (const int*)  d_in[1];
    const int*   etype   = (const int*)  d_in[2];
    const int*   batch   = (const int*)  d_in[4];
    const float* basis   = (const float*)d_in[6];
    const float* comp    = (const float*)d_in[7];
    const float* root    = (const float*)d_in[8];
    const float* bias    = (const float*)d_in[9];
    const float* fc_w    = (const float*)d_in[10];
    const float* fc_b    = (const float*)d_in[11];

    int N  = in_sizes[4];          // 50000
    int E  = in_sizes[2];          // 600000
    int C  = in_sizes[11];         // 16
    int G  = out_size / C;         // 64
    int IO = in_sizes[8];          // 16384
    int B  = in_sizes[6] / IO;     // 4
    int R  = in_sizes[7] / B;      // 8
    int NR = N * R;
    int Mpad = ceil_div(N, 128) * 128;

    const int* src = eindex;
    const int* dst = eindex + E;

    // ---- workspace layout (total ~134.1 MB, <= round-2 proven footprint) ----
    char* base = (char*)d_ws;
    size_t off = 0;
    auto alloc = [&](size_t bytes) -> char* {
        char* p = base + off;
        off = align_up(off + bytes, 256);
        return p;
    };
    unsigned short* Bt  = (unsigned short*)alloc(sizeof(unsigned short)*128*1152);
    int*   cnt      = (int*)  alloc(sizeof(int)*(size_t)NR);          // also cursor
    int*   offsets  = (int*)  alloc(sizeof(int)*((size_t)NR+1));
    int*   bsums    = (int*)  alloc(sizeof(int)*1024);
    int*   slot_src = (int*)  alloc(sizeof(int)*(size_t)E);
    unsigned short* h = (unsigned short*)alloc(sizeof(unsigned short)*(size_t)Mpad*128);
    float* psum     = (float*)alloc(sizeof(float)*(size_t)G*128);
    int*   start    = (int*)  alloc(sizeof(int)*((size_t)G+1));
    unsigned int* Mc = (unsigned int*)alloc(sizeof(unsigned short)*(size_t)Mpad*1152);

    // ---- pipeline ----
    hipMemsetAsync(cnt, 0, sizeof(int)*(size_t)NR, stream);
    compute_Bt_kernel<<<ceil_div(128*1152,256),256,0,stream>>>(comp, basis, root, Bt, B);
    count_kernel<<<ceil_div(E,256),256,0,stream>>>(dst, etype, cnt, E, R);

    int nb = ceil_div(NR, 1024);
    scan_block_kernel<<<nb,256,0,stream>>>(cnt, offsets, bsums, NR);
    scan_block_kernel<<<1,256,0,stream>>>(bsums, bsums, nullptr, nb);
    scan_add_kernel<<<ceil_div(NR,256),256,0,stream>>>(offsets, bsums, NR, E);

    hipMemsetAsync(cnt, 0, sizeof(int)*(size_t)NR, stream);  // reuse as cursor
    fill_kernel<<<ceil_div(E,256),256,0,stream>>>(src, dst, etype, offsets, cnt, slot_src, E, R);

    xb_kernel<<<ceil_div(N*64,256),256,0,stream>>>(x, Mc, N);
    aggregate_kernel<<<ceil_div(N*64,256),256,0,stream>>>(offsets, slot_src, Mc, N, R);

    mfma_gemm_kernel<<<ceil_div(N,128),256,0,stream>>>((const unsigned short*)Mc, Bt, bias, h, N);

    hipMemsetAsync(psum, 0, sizeof(float)*(size_t)G*128, stream);
    bounds_kernel<<<1,128,0,stream>>>(batch, start, N, G);
    pool_kernel2<<<dim3(G,8),256,0,stream>>>((const unsigned int*)h, start, psum);
    fc_kernel<<<ceil_div(G*C,256),256,0,stream>>>(psum, start, fc_w, fc_b, (float*)d_out, G, 128, C);
}